// Round 1
// baseline (108.036 us; speedup 1.0000x reference)
//
#include <hip/hip_runtime.h>
#include <cstdint>
#include <cstddef>

// SpectralGraphConv: B=8, N=1024, C_IN=C_OUT=64, K=4
//   z0 = x, z1 = L x, z_k = 2 L z_{k-1} - z_{k-2}
//   out = sum_k z_k @ theta[k]
//
// Strategy: bf16 MFMA (16x16x32) with f32 accumulation.
// - prep kernel: x -> xT (bf16, [b][c][n]) and theta -> thetaT (bf16, [k][o][c])
//   because MFMA B-fragments want K-contiguous data per lane.
// - stage kernel (x3, one per L-multiply): z_next = alpha * L @ z_in - z_prev,
//   writes z_nextT (bf16) for the next stage, and fuses out += z_next @ theta[k]
//   (stage 1 also adds x @ theta[0]).

typedef __bf16 bf16;
typedef bf16 bf16x8 __attribute__((ext_vector_type(8)));   // MFMA A/B frag (4 VGPRs)
typedef bf16 bf16x4 __attribute__((ext_vector_type(4)));   // 8-byte pack
typedef float f32x4 __attribute__((ext_vector_type(4)));   // MFMA C/D frag

#define MFMA_BF16(a, b, c) __builtin_amdgcn_mfma_f32_16x16x32_bf16((a), (b), (c), 0, 0, 0)

// ---------------------------------------------------------------------------
// prep: 64x64 f32->bf16 transposes.
// blocks 0..127: x[b][n0:n0+64][0:64] -> xT[b][c][n0:n0+64]
// blocks 128..131: theta[k][c][o] -> thetaT[k][o][c]
// ---------------------------------------------------------------------------
__global__ __launch_bounds__(256) void prep_kernel(const float* __restrict__ x,
                                                   const float* __restrict__ theta,
                                                   bf16* __restrict__ xT,
                                                   bf16* __restrict__ thT)
{
    __shared__ bf16 tile[64][72];   // +8 pad: break bank-conflict stride
    const int bid = blockIdx.x;
    const float* src;
    bf16* dst;
    int dst_ld;
    if (bid < 128) {
        const int b = bid >> 4;
        const int n0 = (bid & 15) << 6;
        src = x + ((size_t)(b * 1024 + n0)) * 64;     // [64 n][64 c]
        dst = xT + (size_t)b * 64 * 1024 + n0;        // elem (c, n): c*1024 + n
        dst_ld = 1024;
    } else {
        const int k = bid - 128;
        src = theta + (size_t)k * 4096;               // [64 c][64 o]
        dst = thT + (size_t)k * 4096;                 // elem (o, c): o*64 + c
        dst_ld = 64;
    }
    const int t = threadIdx.x;
    const int r = t >> 2;            // 0..63 (source row)
    const int c0 = (t & 3) << 4;     // 0,16,32,48 (source col chunk)
#pragma unroll
    for (int j = 0; j < 16; j += 4) {
        f32x4 v = *reinterpret_cast<const f32x4*>(src + r * 64 + c0 + j);
        tile[r][c0 + j + 0] = (bf16)v[0];
        tile[r][c0 + j + 1] = (bf16)v[1];
        tile[r][c0 + j + 2] = (bf16)v[2];
        tile[r][c0 + j + 3] = (bf16)v[3];
    }
    __syncthreads();
    // write dst[cc=r][rr=c0..c0+16] = tile[rr][cc]
    bf16x8 o0, o1;
#pragma unroll
    for (int j = 0; j < 8; ++j) {
        o0[j] = tile[c0 + j][r];
        o1[j] = tile[c0 + 8 + j][r];
    }
    *reinterpret_cast<bf16x8*>(dst + (size_t)r * dst_ld + c0) = o0;
    *reinterpret_cast<bf16x8*>(dst + (size_t)r * dst_ld + c0 + 8) = o1;
}

// ---------------------------------------------------------------------------
// stage kernel: one 32-row M-tile of one batch per workgroup.
//   acc = L[b][m0:m0+32][:] @ zin[b]          (MFMA over K=1024, BK=64)
//   z   = alpha*acc - zprev                    (alpha=1 stage1, 2 otherwise)
//   zoutT written (stages 1,2); out += z @ theta[k] (+ x @ theta[0] on stage 1)
// 4 waves; wave w owns channel columns [16w, 16w+16).
// ---------------------------------------------------------------------------
template <int STAGE>
__global__ __launch_bounds__(256) void stage_kernel(
    const float* __restrict__ Lmat,
    const float* __restrict__ x,
    const bf16* __restrict__ zinT,     // [b][c][n]  (B operand, K-contig)
    const bf16* __restrict__ zprevT,   // [b][c][n]  (subtract term, stages 2,3)
    const bf16* __restrict__ thT,      // [k][o][c]
    bf16* __restrict__ zoutT,          // [b][c][n]  (stages 1,2)
    float* __restrict__ out)           // [b][n][o] f32
{
    __shared__ bf16 A_lds[32 * 72];    // 32 rows x BK=64, stride 72 (2-way conflicts only)

    const int bid = blockIdx.x;
    const int b  = bid >> 5;
    const int m0 = (bid & 31) << 5;
    const int t  = threadIdx.x;
    const int w  = t >> 6;             // wave id 0..3 -> channel group
    const int l  = t & 63;
    const int l15 = l & 15;
    const int lg  = l >> 4;            // lane group 0..3

    const float* Lb  = Lmat + (size_t)b * (1024 * 1024);
    const bf16*  zin = zinT + (size_t)b * (64 * 1024);

    // staging: thread loads L row (m0+sr), 8 consecutive f32 at col sc
    const int sr = t >> 3;
    const int sc = (t & 7) << 3;
    const float* lrow = Lb + (size_t)(m0 + sr) * 1024 + sc;
    // B-frag base: channel row (w*16+l15) of zinT, k-offset lg*8
    const bf16* bptr = zin + (size_t)(w * 16 + l15) * 1024 + lg * 8;

    f32x4 acc0 = {0.f, 0.f, 0.f, 0.f};
    f32x4 acc1 = {0.f, 0.f, 0.f, 0.f};

    // prefetched A registers
    f32x4 av0 = *reinterpret_cast<const f32x4*>(lrow + 0);
    f32x4 av1 = *reinterpret_cast<const f32x4*>(lrow + 4);

    for (int k0 = 0; k0 < 1024; k0 += 64) {
        // current-iter B frags (L2-hot) + next-iter A prefetch
        bf16x8 bfr0 = *reinterpret_cast<const bf16x8*>(bptr + k0);
        bf16x8 bfr1 = *reinterpret_cast<const bf16x8*>(bptr + k0 + 32);
        f32x4 nv0, nv1;
        if (k0 + 64 < 1024) {
            nv0 = *reinterpret_cast<const f32x4*>(lrow + k0 + 64);
            nv1 = *reinterpret_cast<const f32x4*>(lrow + k0 + 68);
        }
        __syncthreads();               // previous iteration's LDS reads done
        bf16x8 apk;
        apk[0] = (bf16)av0[0]; apk[1] = (bf16)av0[1];
        apk[2] = (bf16)av0[2]; apk[3] = (bf16)av0[3];
        apk[4] = (bf16)av1[0]; apk[5] = (bf16)av1[1];
        apk[6] = (bf16)av1[2]; apk[7] = (bf16)av1[3];
        *reinterpret_cast<bf16x8*>(&A_lds[sr * 72 + sc]) = apk;
        __syncthreads();
        // A frags: row = mf*16 + l15, k = kk*32 + lg*8 (k-contiguous)
        bf16x8 a00 = *reinterpret_cast<const bf16x8*>(&A_lds[(l15) * 72 + lg * 8]);
        bf16x8 a01 = *reinterpret_cast<const bf16x8*>(&A_lds[(l15) * 72 + 32 + lg * 8]);
        bf16x8 a10 = *reinterpret_cast<const bf16x8*>(&A_lds[(16 + l15) * 72 + lg * 8]);
        bf16x8 a11 = *reinterpret_cast<const bf16x8*>(&A_lds[(16 + l15) * 72 + 32 + lg * 8]);
        acc0 = MFMA_BF16(a00, bfr0, acc0);
        acc0 = MFMA_BF16(a01, bfr1, acc0);
        acc1 = MFMA_BF16(a10, bfr0, acc1);
        acc1 = MFMA_BF16(a11, bfr1, acc1);
        av0 = nv0;
        av1 = nv1;
    }

    // epilogue: z = alpha*acc - zprev   (C/D frag: row=(lg)*4+r, col=l15)
    const int c = w * 16 + l15;
    const float alpha = (STAGE == 1) ? 1.0f : 2.0f;
    f32x4 z0v, z1v;
    {
        f32x4 zp0 = {0.f, 0.f, 0.f, 0.f};
        f32x4 zp1 = {0.f, 0.f, 0.f, 0.f};
        if constexpr (STAGE >= 2) {
            const bf16* zpb = zprevT + (size_t)(b * 64 + c) * 1024 + m0 + lg * 4;
            bf16x4 p0 = *reinterpret_cast<const bf16x4*>(zpb);
            bf16x4 p1 = *reinterpret_cast<const bf16x4*>(zpb + 16);
#pragma unroll
            for (int r = 0; r < 4; ++r) { zp0[r] = (float)p0[r]; zp1[r] = (float)p1[r]; }
        }
#pragma unroll
        for (int r = 0; r < 4; ++r) {
            z0v[r] = alpha * acc0[r] - zp0[r];
            z1v[r] = alpha * acc1[r] - zp1[r];
        }
    }
    if constexpr (STAGE <= 2) {
        bf16* zob = zoutT + (size_t)(b * 64 + c) * 1024 + m0 + lg * 4;
        bf16x4 q0, q1;
#pragma unroll
        for (int r = 0; r < 4; ++r) { q0[r] = (bf16)z0v[r]; q1[r] = (bf16)z1v[r]; }
        *reinterpret_cast<bf16x4*>(zob) = q0;
        *reinterpret_cast<bf16x4*>(zob + 16) = q1;
    }

    // -------- theta phase: out(+)= z @ theta[k]  (+ x @ theta[0] on stage 1) ----
    __syncthreads();   // all waves done reading last A tile
    // relayout z tile into LDS row-major [m][ch], stride 72 (A-frag wants c-contig)
#pragma unroll
    for (int r = 0; r < 4; ++r) {
        A_lds[(lg * 4 + r) * 72 + c]      = (bf16)z0v[r];
        A_lds[(16 + lg * 4 + r) * 72 + c] = (bf16)z1v[r];
    }
    __syncthreads();

    f32x4 oa0, oa1;
    if constexpr (STAGE == 1) {
        oa0 = (f32x4){0.f, 0.f, 0.f, 0.f};
        oa1 = (f32x4){0.f, 0.f, 0.f, 0.f};
        // x @ theta[0]: A frags straight from f32 x (row m, c-contiguous)
#pragma unroll
        for (int ck = 0; ck < 2; ++ck) {
            bf16x8 bt = *reinterpret_cast<const bf16x8*>(
                thT + (size_t)(0 * 64 + w * 16 + l15) * 64 + ck * 32 + lg * 8);
            const float* xp0 = x + (size_t)(b * 1024 + m0 + l15) * 64 + ck * 32 + lg * 8;
            const float* xp1 = xp0 + (size_t)16 * 64;
            f32x4 u0 = *reinterpret_cast<const f32x4*>(xp0);
            f32x4 u1 = *reinterpret_cast<const f32x4*>(xp0 + 4);
            f32x4 v0 = *reinterpret_cast<const f32x4*>(xp1);
            f32x4 v1 = *reinterpret_cast<const f32x4*>(xp1 + 4);
            bf16x8 ax0, ax1;
#pragma unroll
            for (int j = 0; j < 4; ++j) {
                ax0[j] = (bf16)u0[j]; ax0[4 + j] = (bf16)u1[j];
                ax1[j] = (bf16)v0[j]; ax1[4 + j] = (bf16)v1[j];
            }
            oa0 = MFMA_BF16(ax0, bt, oa0);
            oa1 = MFMA_BF16(ax1, bt, oa1);
        }
    } else {
        // accumulate onto existing out
#pragma unroll
        for (int r = 0; r < 4; ++r) {
            oa0[r] = out[(size_t)(b * 1024 + m0 + lg * 4 + r) * 64 + w * 16 + l15];
            oa1[r] = out[(size_t)(b * 1024 + m0 + 16 + lg * 4 + r) * 64 + w * 16 + l15];
        }
    }
    constexpr int KTH = (STAGE == 1) ? 1 : STAGE;
#pragma unroll
    for (int ck = 0; ck < 2; ++ck) {
        bf16x8 bt = *reinterpret_cast<const bf16x8*>(
            thT + (size_t)(KTH * 64 + w * 16 + l15) * 64 + ck * 32 + lg * 8);
        bf16x8 az0 = *reinterpret_cast<const bf16x8*>(&A_lds[l15 * 72 + ck * 32 + lg * 8]);
        bf16x8 az1 = *reinterpret_cast<const bf16x8*>(&A_lds[(16 + l15) * 72 + ck * 32 + lg * 8]);
        oa0 = MFMA_BF16(az0, bt, oa0);
        oa1 = MFMA_BF16(az1, bt, oa1);
    }
#pragma unroll
    for (int r = 0; r < 4; ++r) {
        out[(size_t)(b * 1024 + m0 + lg * 4 + r) * 64 + w * 16 + l15]      = oa0[r];
        out[(size_t)(b * 1024 + m0 + 16 + lg * 4 + r) * 64 + w * 16 + l15] = oa1[r];
    }
}

// ---------------------------------------------------------------------------
extern "C" void kernel_launch(void* const* d_in, const int* in_sizes, int n_in,
                              void* d_out, int out_size, void* d_ws, size_t ws_size,
                              hipStream_t stream)
{
    const float* x  = (const float*)d_in[0];    // [8,1024,64]
    const float* L  = (const float*)d_in[1];    // [8,1024,1024]
    const float* th = (const float*)d_in[2];    // [4,64,64]
    float* out = (float*)d_out;                 // [8,1024,64]

    // workspace layout (bf16): xT | z1T | z2T | thetaT  (~3.2 MB total)
    bf16* xT  = (bf16*)d_ws;
    bf16* z1T = xT  + (size_t)8 * 64 * 1024;
    bf16* z2T = z1T + (size_t)8 * 64 * 1024;
    bf16* thT = z2T + (size_t)8 * 64 * 1024;

    prep_kernel<<<dim3(132), dim3(256), 0, stream>>>(x, th, xT, thT);
    // stage 1: z1 = L x;            out  = x@th0 + z1@th1
    stage_kernel<1><<<dim3(256), dim3(256), 0, stream>>>(L, x, xT, xT, thT, z1T, out);
    // stage 2: z2 = 2 L z1 - x;     out += z2@th2
    stage_kernel<2><<<dim3(256), dim3(256), 0, stream>>>(L, x, z1T, xT, thT, z2T, out);
    // stage 3: z3 = 2 L z2 - z1;    out += z3@th3
    stage_kernel<3><<<dim3(256), dim3(256), 0, stream>>>(L, x, z2T, z1T, thT, z2T, out);
}